// Round 16
// baseline (356.877 us; speedup 1.0000x reference)
//
#include <hip/hip_runtime.h>
#include <hip/hip_bf16.h>
#include <math.h>

// ---------------------------------------------------------------------------
// ModelFC_49134425866355 on MI355X (gfx950)
//
// out0[row] = dot(LN(gelu(E@W1+b1))*g+b, W2[:,sel]) + b2[sel]
//           = rstd*(D - mu*Gw) + Bw     (algebraic LN+GEMV fusion)
//
// r30 change vs r28 champion (301.9us; gemm1p 102us/MfmaUtil 34):
// gemm2m = B-panel sharing across TWO stacked M-tiles. 1536 blocks, each
// computes 256x128 output: per K-step, ONE B staging (was two) and 64 MFMA
// per barrier-drain (was 32) -> the m97-structure's ~20% vmcnt-drain stall
// and per-block prologue/epilogue amortize 2x, B fetch traffic halves.
// Sync structure UNCHANGED (2 barriers/kt) -> no new race surface; per-tile
// math bit-identical (same MFMA order, epilogue run twice via inlined
// lambda so acc indexing stays compile-time-static). LDS 36.9->48KB.
// All other kernels r28-verbatim.
// 4 kernels: prep_duo(+cvt) | own_lnlog(+fin) | gemm2m | out_scores.
// ---------------------------------------------------------------------------

typedef __bf16 bf16_t;
typedef __bf16  bf16x2  __attribute__((ext_vector_type(2)));
typedef __bf16  bf16x8  __attribute__((ext_vector_type(8)));
typedef float   floatx4 __attribute__((ext_vector_type(4)));

__device__ __forceinline__ float gelu_exact(float x) {
    return 0.5f * x * (1.0f + erff(x * 0.7071067811865475f));
}
// tanh-form gelu via sigmoid; |err|<~1e-3, below bf16 rounding of bulk path.
__device__ __forceinline__ float gelu_fast(float x) {
    const float z = x * (1.0f + 0.044715f * x * x);
    return __fdividef(x, 1.0f + __expf(-1.5957691216f * z));
}

// async global->LDS, 16B per lane; lds base wave-uniform (HW adds lane*16).
// OFFSET ARG STAYS 0 — nonzero immediate is unverified and broke round 5.
__device__ __forceinline__ void gl_lds16(const void* g, void* l) {
    __builtin_amdgcn_global_load_lds(
        (const __attribute__((address_space(1))) void*)g,
        (__attribute__((address_space(3))) void*)l, 16, 0, 0);
}

// ---------------------------------------------------------------------------
// prep_duo: [0,288) tr_w1 | [288,544) own_h (full-row) | [544,12832) cvt
// (verbatim r28, measured-good)
// ---------------------------------------------------------------------------
__global__ __launch_bounds__(256) void prep_duo(
        const float* __restrict__ E, const float* __restrict__ W1,
        bf16_t* __restrict__ W1t, float* __restrict__ hpart,
        bf16_t* __restrict__ Ebf) {
    __shared__ alignas(16) char smemc[16640];   // max(sT 64x65 fp32, sE 6KB)
    const int bid = blockIdx.x;
    const int tid = threadIdx.x;

    if (bid >= 544) {                   // ---- E -> bf16 (25,165,824 elems)
        const int cb = bid - 544;       // 0..12287
        const size_t base = ((size_t)cb * 256 + tid) * 8;
        const float4 v0 = *(const float4*)(E + base);
        const float4 v1 = *(const float4*)(E + base + 4);
        bf16x8 o;
        o[0] = (bf16_t)v0.x; o[1] = (bf16_t)v0.y;
        o[2] = (bf16_t)v0.z; o[3] = (bf16_t)v0.w;
        o[4] = (bf16_t)v1.x; o[5] = (bf16_t)v1.y;
        o[6] = (bf16_t)v1.z; o[7] = (bf16_t)v1.w;
        *(bf16x8*)(Ebf + base) = o;
        return;
    }

    if (bid < 288) {                    // ---- tr_w1: 64x64 LDS-tiled transpose
        float* sT = (float*)smemc;      // [64][65]
        const int bk = bid % 12, bn = bid / 12;
        const int k0 = bk * 64, n0 = bn * 64;
        #pragma unroll
        for (int i = 0; i < 16; ++i) {
            const int idx = tid + i * 256;
            const int kk = idx >> 6, nn = idx & 63;
            sT[kk * 65 + nn] = W1[(size_t)(k0 + kk) * 1536 + n0 + nn];
        }
        __syncthreads();
        // vectorized bf16x2 stores: idx covers (nn, kk-pair)
        #pragma unroll
        for (int i = 0; i < 8; ++i) {
            const int idx = tid + i * 256;   // 0..2047
            const int nn = idx >> 5;         // 0..63
            const int kp = (idx & 31) * 2;   // 0,2,..,62
            bf16x2 v;
            v[0] = (bf16_t)sT[kp * 65 + nn];
            v[1] = (bf16_t)sT[(kp + 1) * 65 + nn];
            *(bf16x2*)(W1t + (size_t)(n0 + nn) * 768 + k0 + kp) = v;
        }
    } else {                            // ---- own_h: hpart[kq][512][1536]
        // 256 blocks: (a, kq); each covers ALL 1536 cols (6 cols/thread).
        // Per-column k-order identical -> hpart bit-identical.
        float* sE = (float*)smemc;      // [8][192]
        const int b  = bid - 288;       // 0..255
        const int a  = b & 63;
        const int kq = b >> 6;          // 0..3

        const float* Ebase = E + (size_t)(520 * a) * 768 + kq * 192;
        for (int idx = tid; idx < 1536; idx += 256) {
            const int row = idx / 192, i = idx - row * 192;
            sE[idx] = Ebase[(size_t)row * 768 + i];
        }
        __syncthreads();

        const int c0 = tid * 2;         // 0..510
        const float* w1p = W1 + (size_t)(kq * 192) * 1536 + c0;
        float ax0[8] = {}, ay0[8] = {};
        float ax1[8] = {}, ay1[8] = {};
        float ax2[8] = {}, ay2[8] = {};
        for (int k = 0; k < 192; ++k) {
            const float* wk = w1p + (size_t)k * 1536;
            const float2 w0 = *(const float2*)(wk);
            const float2 w1v = *(const float2*)(wk + 512);
            const float2 w2v = *(const float2*)(wk + 1024);
            #pragma unroll
            for (int j = 0; j < 8; ++j) {
                const float e = sE[j * 192 + k];   // LDS broadcast, shared x3
                ax0[j] += w0.x * e;  ay0[j] += w0.y * e;
                ax1[j] += w1v.x * e; ay1[j] += w1v.y * e;
                ax2[j] += w2v.x * e; ay2[j] += w2v.y * e;
            }
        }
        #pragma unroll
        for (int j = 0; j < 8; ++j) {
            float* hp = hpart + (size_t)(kq * 512 + a * 8 + j) * 1536 + c0;
            *(float2*)(hp)        = make_float2(ax0[j], ay0[j]);
            *(float2*)(hp + 512)  = make_float2(ax1[j], ay1[j]);
            *(float2*)(hp + 1024) = make_float2(ax2[j], ay2[j]);
        }
    }
}

// ---------------------------------------------------------------------------
// own_lnlog: per row (512 blocks x 512 threads). (verbatim r22/r28)
// ---------------------------------------------------------------------------
__global__ __launch_bounds__(512) void own_lnlog(
        const float* __restrict__ hpart, const float* __restrict__ b1,
        const float* __restrict__ lng,  const float* __restrict__ lnb,
        const float* __restrict__ W2,   const float* __restrict__ b2,
        float* __restrict__ out, float* __restrict__ u,
        float* __restrict__ gwbw) {
    __shared__ float srow[1536];
    __shared__ float red16[16];
    __shared__ float redl[384];
    __shared__ float slog[128];
    __shared__ int   ssel;
    const int row = blockIdx.x, tid = threadIdx.x;
    const int lane = tid & 63, wv = tid >> 6;   // wv 0..7

    // ---- gelu(sum of partials + b1), 3 cols/thread
    float x[3];
    #pragma unroll
    for (int i = 0; i < 3; ++i) {
        const int c = tid + i * 512;
        x[i] = gelu_exact(hpart[(size_t)row * 1536 + c]
                        + hpart[(size_t)(512 + row) * 1536 + c]
                        + hpart[(size_t)(1024 + row) * 1536 + c]
                        + hpart[(size_t)(1536 + row) * 1536 + c] + b1[c]);
    }
    float s = x[0] + x[1] + x[2];
    #pragma unroll
    for (int o = 32; o > 0; o >>= 1) s += __shfl_xor(s, o, 64);
    if (lane == 0) red16[wv] = s;
    __syncthreads();
    float mu = 0.f;
    #pragma unroll
    for (int i = 0; i < 8; ++i) mu += red16[i];
    mu *= (1.0f / 1536.0f);

    float s2 = 0.f;
    #pragma unroll
    for (int i = 0; i < 3; ++i) { float d = x[i] - mu; s2 += d * d; }
    #pragma unroll
    for (int o = 32; o > 0; o >>= 1) s2 += __shfl_xor(s2, o, 64);
    if (lane == 0) red16[8 + wv] = s2;
    __syncthreads();
    float v2 = 0.f;
    #pragma unroll
    for (int i = 0; i < 8; ++i) v2 += red16[8 + i];
    const float rstd = rsqrtf(v2 * (1.0f / 1536.0f) + 1e-12f);

    #pragma unroll
    for (int i = 0; i < 3; ++i) {
        const int c = tid + i * 512;
        srow[c] = (x[i] - mu) * rstd * lng[c] + lnb[c];
    }
    __syncthreads();

    // ---- logits: (d, ks) = (128, 4); 384 k-iters each
    const int d  = tid & 127;
    const int ks = tid >> 7;                  // 0..3
    const int dd = d < 100 ? d : 99;
    float acc = (ks == 0) ? b2[dd] : 0.0f;
    const float* hr  = srow + ks * 384;
    const float* w2p = W2 + (size_t)(ks * 384) * 100 + dd;
    #pragma unroll 8
    for (int k = 0; k < 384; ++k)
        acc += hr[k] * w2p[(size_t)k * 100];
    if (ks) redl[(ks - 1) * 128 + d] = acc;
    __syncthreads();
    if (ks == 0) {
        const float tot = acc + redl[d] + redl[128 + d] + redl[256 + d];
        slog[d] = (d < 100) ? tot : -INFINITY;
    }
    __syncthreads();

    // ---- wave 0: softmax max-prob + argmax (first-max tie-break)
    if (wv == 0) {
        const float v0 = slog[lane], v1 = slog[lane + 64];
        float bv; int bi;
        if (v0 >= v1) { bv = v0; bi = lane; } else { bv = v1; bi = lane + 64; }
        #pragma unroll
        for (int o = 1; o < 64; o <<= 1) {
            const float vo = __shfl_xor(bv, o, 64);
            const int   io = __shfl_xor(bi, o, 64);
            if (vo > bv || (vo == bv && io < bi)) { bv = vo; bi = io; }
        }
        float e = expf(v0 - bv) + expf(v1 - bv);   // exp(-inf)=0 pads
        #pragma unroll
        for (int o = 32; o > 0; o >>= 1) e += __shfl_xor(e, o, 64);
        if (lane == 0) {
            out[262144 + row] = 1.0f / e;          // VG_scores
            out[262656 + row] = (float)bi;         // VG_scores_index
            ssel = bi;
        }
    }
    __syncthreads();

    // ---- block 511: sel-derived constants u / Gw / Bw
    if (row == 511) {
        const int sel = ssel;
        float gw = 0.f, bw = 0.f;
        #pragma unroll
        for (int c = tid; c < 1536; c += 512) {
            const float wv2 = W2[(size_t)c * 100 + sel];
            const float uu = lng[c] * wv2;
            u[c] = uu;
            gw += uu;
            bw += lnb[c] * wv2;
        }
        #pragma unroll
        for (int o = 32; o > 0; o >>= 1) {
            gw += __shfl_xor(gw, o, 64);
            bw += __shfl_xor(bw, o, 64);
        }
        if (lane == 0) { red16[wv] = gw; red16[8 + wv] = bw; }
        __syncthreads();
        if (tid == 0) {
            float G = 0.f, B = 0.f;
            #pragma unroll
            for (int i = 0; i < 8; ++i) { G += red16[i]; B += red16[8 + i]; }
            gwbw[0] = G;
            gwbw[1] = B + b2[sel];
        }
    }
}

// ---------------------------------------------------------------------------
// gemm2m: [32768,768]x[768,1536]; each block = 256x128 output (two stacked
// 128x128 M-tiles sharing ONE B staging). BK=64, 12 K-tiles; per kt: 12
// gl_lds (A0,A1,B), 2 barriers, 64 MFMA. Same swizzle/fragment scheme as
// the verified gemm1p; per-tile math bit-identical. Epilogue (stats via
// LDS) runs twice via inlined lambda (compile-time acc selection, rule#20).
// ---------------------------------------------------------------------------
__global__ __launch_bounds__(256) void gemm2m(
        const bf16_t* __restrict__ A, const bf16_t* __restrict__ Bt,
        const float* __restrict__ bias, const float* __restrict__ u,
        float* __restrict__ pS1, float* __restrict__ pS2,
        float* __restrict__ pD) {
    constexpr int K = 768;
    __shared__ alignas(16) char smem[49152];   // sA0|sA1|sB 48KB; epi 36.9KB
    bf16_t* sA0 = (bf16_t*)smem;               // [128][64] bf16, swizzled
    bf16_t* sA1 = (bf16_t*)(smem + 16384);
    bf16_t* sB  = (bf16_t*)(smem + 32768);

    // XCD-aware remap: 12 n-tiles of one m-pair land on one XCD
    const int linear = blockIdx.x;             // 0..1535
    const int xcd  = linear & 7;
    const int slot = linear >> 3;              // 0..191
    const int bx = slot % 12;
    const int bp = (slot / 12) * 8 + xcd;      // 0..127
    const int m0 = bp * 256;
    const int n0 = bx * 128;

    const int tid  = threadIdx.x;
    const int lane = tid & 63;
    const int wave = tid >> 6;
    const int wr = wave >> 1, wc = wave & 1;
    const int q  = lane >> 4;
    const int l15 = lane & 15;

    // ---- staging bases (8 granules/row, swizzle gcol = col ^ (row&7))
    const bf16_t* gA0[4]; bf16_t* lA0[4];
    const bf16_t* gA1[4]; bf16_t* lA1[4];
    const bf16_t* gB[4];  bf16_t* lB[4];
    #pragma unroll
    for (int c = 0; c < 4; ++c) {
        const int s    = c * 256 + tid;
        const int row  = s >> 3;
        const int col  = s & 7;
        const int gcol = col ^ (row & 7);
        gA0[c] = A  + (size_t)(m0 + row) * K + gcol * 8;
        gA1[c] = A  + (size_t)(m0 + 128 + row) * K + gcol * 8;
        gB[c]  = Bt + (size_t)(n0 + row) * K + gcol * 8;
        lA0[c] = sA0 + (c * 256 + wave * 64) * 8;
        lA1[c] = sA1 + (c * 256 + wave * 64) * 8;
        lB[c]  = sB  + (c * 256 + wave * 64) * 8;
    }
    // ---- read bases (K-step invariant); row&7 == lane&7 for both
    const bf16_t* rA0[4]; const bf16_t* rA1[4]; const bf16_t* rB[4];
    #pragma unroll
    for (int t4 = 0; t4 < 4; ++t4) {
        rA0[t4] = sA0 + (wr * 64 + t4 * 16 + l15) * 64;
        rA1[t4] = sA1 + (wr * 64 + t4 * 16 + l15) * 64;
        rB[t4]  = sB  + (wc * 64 + t4 * 16 + l15) * 64;
    }
    const int c0 = ((q)     ^ (lane & 7)) * 8;   // ks=0 fragment offset
    const int c1 = ((4 + q) ^ (lane & 7)) * 8;   // ks=1 fragment offset

    floatx4 acc0[4][4] = {};
    floatx4 acc1[4][4] = {};

    #pragma unroll
    for (int kt = 0; kt < 12; ++kt) {
        const int k0 = kt * 64;
        __syncthreads();   // prev compute done before LDS overwrite
        #pragma unroll
        for (int c = 0; c < 4; ++c) gl_lds16(gB[c] + k0, lB[c]);
        #pragma unroll
        for (int c = 0; c < 4; ++c) gl_lds16(gA0[c] + k0, lA0[c]);
        #pragma unroll
        for (int c = 0; c < 4; ++c) gl_lds16(gA1[c] + k0, lA1[c]);
        __syncthreads();   // drain DMA, then barrier

        #pragma unroll
        for (int ks = 0; ks < 2; ++ks) {
            const int co = ks ? c1 : c0;
            bf16x8 af0[4], af1[4], bfr[4];
            #pragma unroll
            for (int t4 = 0; t4 < 4; ++t4) {
                af0[t4] = *(const bf16x8*)(rA0[t4] + co);
                af1[t4] = *(const bf16x8*)(rA1[t4] + co);
                bfr[t4] = *(const bf16x8*)(rB[t4] + co);
            }
            #pragma unroll
            for (int mt = 0; mt < 4; ++mt)
                #pragma unroll
                for (int nt = 0; nt < 4; ++nt)
                    acc0[mt][nt] = __builtin_amdgcn_mfma_f32_16x16x32_bf16(
                        af0[mt], bfr[nt], acc0[mt][nt], 0, 0, 0);
            #pragma unroll
            for (int mt = 0; mt < 4; ++mt)
                #pragma unroll
                for (int nt = 0; nt < 4; ++nt)
                    acc1[mt][nt] = __builtin_amdgcn_mfma_f32_16x16x32_bf16(
                        af1[mt], bfr[nt], acc1[mt][nt], 0, 0, 0);
        }
    }

    // ---- stats epilogue via LDS, run per M-tile. C/D: col=l15, row=q*4+r.
    float bias4[4];
    #pragma unroll
    for (int nt = 0; nt < 4; ++nt) bias4[nt] = bias[n0 + wc * 64 + nt * 16 + l15];

    auto epilogue = [&](floatx4 (&acc)[4][4], int mbase) {
        __syncthreads();                       // prior smem readers done
        bf16_t* sh = (bf16_t*)smem;            // [128][130] bf16 = 33280 B
        float*  su = (float*)(smem + 33280);   // u[n0..n0+127]       512 B
        float*  sp = (float*)(smem + 33792);   // [256][3] partials  3072 B

        if (tid < 128) su[tid] = u[n0 + tid];

        #pragma unroll
        for (int mt = 0; mt < 4; ++mt)
            #pragma unroll
            for (int nt = 0; nt < 4; ++nt)
                #pragma unroll
                for (int r = 0; r < 4; ++r) {
                    const int rowl = wr * 64 + mt * 16 + q * 4 + r;
                    const int coll = wc * 64 + nt * 16 + l15;
                    sh[rowl * 130 + coll] = (bf16_t)gelu_fast(acc[mt][nt][r] + bias4[nt]);
                }
        __syncthreads();

        // phase 2: thread = (row, half); reduce 64 cols each
        {
            const int rowl = tid >> 1, half = tid & 1;
            const bf16_t* hp = sh + rowl * 130 + half * 64;
            const float*  up = su + half * 64;
            float s1 = 0.f, s2 = 0.f, dd = 0.f;
            #pragma unroll
            for (int c = 0; c < 64; ++c) {
                const float v = (float)hp[c];
                s1 += v; s2 += v * v; dd += v * up[c];
            }
            sp[tid * 3 + 0] = s1; sp[tid * 3 + 1] = s2; sp[tid * 3 + 2] = dd;
        }
        __syncthreads();
        if (tid < 128) {
            const float* p0 = sp + (2 * tid) * 3;
            const float* p1 = sp + (2 * tid + 1) * 3;
            const size_t idx = (size_t)bx * 32768 + (mbase + tid);
            pS1[idx] = p0[0] + p1[0];
            pS2[idx] = p0[1] + p1[1];
            pD[idx]  = p0[2] + p1[2];
        }
    };
    epilogue(acc0, m0);
    epilogue(acc1, m0 + 128);
}

// ---------------------------------------------------------------------------
// out_scores: out[t*8+k] = rstd*(D - mu*Gw) + Bw   (32768 threads)
// ---------------------------------------------------------------------------
__global__ __launch_bounds__(256) void out_scores(
        const float* __restrict__ pS1, const float* __restrict__ pS2,
        const float* __restrict__ pD,  const float* __restrict__ gwbw,
        float* __restrict__ out) {
    const int t = blockIdx.x * 256 + threadIdx.x;   // 32768 exactly
    float s1 = 0.f, s2 = 0.f, d = 0.f;
    #pragma unroll
    for (int nt = 0; nt < 12; ++nt) {
        const size_t idx = (size_t)nt * 32768 + t;
        s1 += pS1[idx]; s2 += pS2[idx]; d += pD[idx];
    }
    const float mu   = s1 * (1.0f / 1536.0f);
    const float var  = s2 * (1.0f / 1536.0f) - mu * mu;
    const float rstd = rsqrtf(var + 1e-12f);
    const float v = rstd * (d - mu * gwbw[0]) + gwbw[1];
    const float4 f = make_float4(v, v, v, v);
    float4* o = (float4*)(out + (size_t)t * 8);
    o[0] = f; o[1] = f;
}

// ---------------------------------------------------------------------------
extern "C" void kernel_launch(void* const* d_in, const int* in_sizes, int n_in,
                              void* d_out, int out_size, void* d_ws, size_t ws_size,
                              hipStream_t stream) {
    const float* E   = (const float*)d_in[0];
    const float* W1  = (const float*)d_in[1];
    const float* b1  = (const float*)d_in[2];
    const float* lng = (const float*)d_in[3];
    const float* lnb = (const float*)d_in[4];
    const float* W2  = (const float*)d_in[5];
    const float* b2  = (const float*)d_in[6];
    float* out = (float*)d_out;

    char* w = (char*)d_ws;
    auto carve = [&](size_t bytes) {
        void* p = (void*)w;
        w += (bytes + 255) & ~(size_t)255;
        return p;
    };
    bf16_t* W1t   = (bf16_t*)carve((size_t)1536 * 768 * 2);    //  2.4 MB
    bf16_t* Ebf   = (bf16_t*)carve((size_t)32768 * 768 * 2);   // 50.3 MB
    float*  u     = (float*)carve(1536 * 4);
    float*  gwbw  = (float*)carve(256);
    // Union region: hpart (12.6 MB, written by prep_duo, dead after
    // own_lnlog) overlaps pS1/pS2/pD (4.7 MB, first written by gemm2m,
    // which runs after own_lnlog) — disjoint lifetimes.
    char*   unionr = (char*)carve((size_t)4 * 512 * 1536 * 4); // 12.6 MB
    float*  hpart = (float*)unionr;
    float*  pS1   = (float*)unionr;
    float*  pS2   = (float*)(unionr + (size_t)12 * 32768 * 4);
    float*  pD    = (float*)(unionr + (size_t)24 * 32768 * 4);

    // 1) prep: W1 transpose + own-row k-partials + E->bf16 (fused grid)
    prep_duo<<<12832, 256, 0, stream>>>(E, W1, W1t, hpart, Ebf);
    // 2) own rows: gelu+LN+logits+softmax/argmax; block 511 -> u/Gw/Bw
    own_lnlog<<<512, 512, 0, stream>>>(hpart, b1, lng, lnb, W2, b2,
                                       out, u, gwbw);
    // 3) fused GEMM, two M-tiles per block sharing B staging
    gemm2m<<<1536, 256, 0, stream>>>(Ebf, W1t, b1, u, pS1, pS2, pD);
    // 4) combine partials -> output 0
    out_scores<<<128, 256, 0, stream>>>(pS1, pS2, pD, gwbw, out);
}

// Round 17
// 322.910 us; speedup vs baseline: 1.1052x; 1.1052x over previous
//
#include <hip/hip_runtime.h>
#include <hip/hip_bf16.h>
#include <math.h>

// ---------------------------------------------------------------------------
// ModelFC_49134425866355 on MI355X (gfx950)
//
// out0[row] = dot(LN(gelu(E@W1+b1))*g+b, W2[:,sel]) + b2[sel]
//           = rstd*(D - mu*Gw) + Bw     (algebraic LN+GEMV fusion)
//
// r32 = r28 champion (301.9us) + in-register gemm epilogue.
// r30's gemm2m died of UNIFIED-FILE register pressure (140 VGPR + 128 AGPR
// = 268/wave -> 1 wave/SIMD -> Occ 11.6%, 223us). Reverted to gemm1p
// (84+64=148 -> 3 waves/SIMD). Change this round: the stats epilogue no
// longer round-trips a 33KB bf16 act tile through LDS (64 scalar
// ds_read_u16 per thread); instead each thread nt-sums its fragments
// in-register and tree-reduces across its 16-lane col group via shfl_xor
// (C/D layout col=l15, row=q*4+r); only a 3KB sred combine remains.
// Per-term math identical; only fp32 row-sum ORDER changes (<=1e-6).
// 4 kernels: prep_duo(+cvt) | own_lnlog(+fin) | gemm1p | out_scores.
// ---------------------------------------------------------------------------

typedef __bf16 bf16_t;
typedef __bf16  bf16x2  __attribute__((ext_vector_type(2)));
typedef __bf16  bf16x8  __attribute__((ext_vector_type(8)));
typedef float   floatx4 __attribute__((ext_vector_type(4)));

__device__ __forceinline__ float gelu_exact(float x) {
    return 0.5f * x * (1.0f + erff(x * 0.7071067811865475f));
}
// tanh-form gelu via sigmoid; |err|<~1e-3, below bf16 rounding of bulk path.
__device__ __forceinline__ float gelu_fast(float x) {
    const float z = x * (1.0f + 0.044715f * x * x);
    return __fdividef(x, 1.0f + __expf(-1.5957691216f * z));
}

// async global->LDS, 16B per lane; lds base wave-uniform (HW adds lane*16).
// OFFSET ARG STAYS 0 — nonzero immediate is unverified and broke round 5.
__device__ __forceinline__ void gl_lds16(const void* g, void* l) {
    __builtin_amdgcn_global_load_lds(
        (const __attribute__((address_space(1))) void*)g,
        (__attribute__((address_space(3))) void*)l, 16, 0, 0);
}

// ---------------------------------------------------------------------------
// prep_duo: [0,288) tr_w1 | [288,544) own_h (full-row) | [544,12832) cvt
// (verbatim r28, measured-good)
// ---------------------------------------------------------------------------
__global__ __launch_bounds__(256) void prep_duo(
        const float* __restrict__ E, const float* __restrict__ W1,
        bf16_t* __restrict__ W1t, float* __restrict__ hpart,
        bf16_t* __restrict__ Ebf) {
    __shared__ alignas(16) char smemc[16640];   // max(sT 64x65 fp32, sE 6KB)
    const int bid = blockIdx.x;
    const int tid = threadIdx.x;

    if (bid >= 544) {                   // ---- E -> bf16 (25,165,824 elems)
        const int cb = bid - 544;       // 0..12287
        const size_t base = ((size_t)cb * 256 + tid) * 8;
        const float4 v0 = *(const float4*)(E + base);
        const float4 v1 = *(const float4*)(E + base + 4);
        bf16x8 o;
        o[0] = (bf16_t)v0.x; o[1] = (bf16_t)v0.y;
        o[2] = (bf16_t)v0.z; o[3] = (bf16_t)v0.w;
        o[4] = (bf16_t)v1.x; o[5] = (bf16_t)v1.y;
        o[6] = (bf16_t)v1.z; o[7] = (bf16_t)v1.w;
        *(bf16x8*)(Ebf + base) = o;
        return;
    }

    if (bid < 288) {                    // ---- tr_w1: 64x64 LDS-tiled transpose
        float* sT = (float*)smemc;      // [64][65]
        const int bk = bid % 12, bn = bid / 12;
        const int k0 = bk * 64, n0 = bn * 64;
        #pragma unroll
        for (int i = 0; i < 16; ++i) {
            const int idx = tid + i * 256;
            const int kk = idx >> 6, nn = idx & 63;
            sT[kk * 65 + nn] = W1[(size_t)(k0 + kk) * 1536 + n0 + nn];
        }
        __syncthreads();
        // vectorized bf16x2 stores: idx covers (nn, kk-pair)
        #pragma unroll
        for (int i = 0; i < 8; ++i) {
            const int idx = tid + i * 256;   // 0..2047
            const int nn = idx >> 5;         // 0..63
            const int kp = (idx & 31) * 2;   // 0,2,..,62
            bf16x2 v;
            v[0] = (bf16_t)sT[kp * 65 + nn];
            v[1] = (bf16_t)sT[(kp + 1) * 65 + nn];
            *(bf16x2*)(W1t + (size_t)(n0 + nn) * 768 + k0 + kp) = v;
        }
    } else {                            // ---- own_h: hpart[kq][512][1536]
        // 256 blocks: (a, kq); each covers ALL 1536 cols (6 cols/thread).
        // Per-column k-order identical -> hpart bit-identical.
        float* sE = (float*)smemc;      // [8][192]
        const int b  = bid - 288;       // 0..255
        const int a  = b & 63;
        const int kq = b >> 6;          // 0..3

        const float* Ebase = E + (size_t)(520 * a) * 768 + kq * 192;
        for (int idx = tid; idx < 1536; idx += 256) {
            const int row = idx / 192, i = idx - row * 192;
            sE[idx] = Ebase[(size_t)row * 768 + i];
        }
        __syncthreads();

        const int c0 = tid * 2;         // 0..510
        const float* w1p = W1 + (size_t)(kq * 192) * 1536 + c0;
        float ax0[8] = {}, ay0[8] = {};
        float ax1[8] = {}, ay1[8] = {};
        float ax2[8] = {}, ay2[8] = {};
        for (int k = 0; k < 192; ++k) {
            const float* wk = w1p + (size_t)k * 1536;
            const float2 w0 = *(const float2*)(wk);
            const float2 w1v = *(const float2*)(wk + 512);
            const float2 w2v = *(const float2*)(wk + 1024);
            #pragma unroll
            for (int j = 0; j < 8; ++j) {
                const float e = sE[j * 192 + k];   // LDS broadcast, shared x3
                ax0[j] += w0.x * e;  ay0[j] += w0.y * e;
                ax1[j] += w1v.x * e; ay1[j] += w1v.y * e;
                ax2[j] += w2v.x * e; ay2[j] += w2v.y * e;
            }
        }
        #pragma unroll
        for (int j = 0; j < 8; ++j) {
            float* hp = hpart + (size_t)(kq * 512 + a * 8 + j) * 1536 + c0;
            *(float2*)(hp)        = make_float2(ax0[j], ay0[j]);
            *(float2*)(hp + 512)  = make_float2(ax1[j], ay1[j]);
            *(float2*)(hp + 1024) = make_float2(ax2[j], ay2[j]);
        }
    }
}

// ---------------------------------------------------------------------------
// own_lnlog: per row (512 blocks x 512 threads). (verbatim r22/r28)
// ---------------------------------------------------------------------------
__global__ __launch_bounds__(512) void own_lnlog(
        const float* __restrict__ hpart, const float* __restrict__ b1,
        const float* __restrict__ lng,  const float* __restrict__ lnb,
        const float* __restrict__ W2,   const float* __restrict__ b2,
        float* __restrict__ out, float* __restrict__ u,
        float* __restrict__ gwbw) {
    __shared__ float srow[1536];
    __shared__ float red16[16];
    __shared__ float redl[384];
    __shared__ float slog[128];
    __shared__ int   ssel;
    const int row = blockIdx.x, tid = threadIdx.x;
    const int lane = tid & 63, wv = tid >> 6;   // wv 0..7

    // ---- gelu(sum of partials + b1), 3 cols/thread
    float x[3];
    #pragma unroll
    for (int i = 0; i < 3; ++i) {
        const int c = tid + i * 512;
        x[i] = gelu_exact(hpart[(size_t)row * 1536 + c]
                        + hpart[(size_t)(512 + row) * 1536 + c]
                        + hpart[(size_t)(1024 + row) * 1536 + c]
                        + hpart[(size_t)(1536 + row) * 1536 + c] + b1[c]);
    }
    float s = x[0] + x[1] + x[2];
    #pragma unroll
    for (int o = 32; o > 0; o >>= 1) s += __shfl_xor(s, o, 64);
    if (lane == 0) red16[wv] = s;
    __syncthreads();
    float mu = 0.f;
    #pragma unroll
    for (int i = 0; i < 8; ++i) mu += red16[i];
    mu *= (1.0f / 1536.0f);

    float s2 = 0.f;
    #pragma unroll
    for (int i = 0; i < 3; ++i) { float d = x[i] - mu; s2 += d * d; }
    #pragma unroll
    for (int o = 32; o > 0; o >>= 1) s2 += __shfl_xor(s2, o, 64);
    if (lane == 0) red16[8 + wv] = s2;
    __syncthreads();
    float v2 = 0.f;
    #pragma unroll
    for (int i = 0; i < 8; ++i) v2 += red16[8 + i];
    const float rstd = rsqrtf(v2 * (1.0f / 1536.0f) + 1e-12f);

    #pragma unroll
    for (int i = 0; i < 3; ++i) {
        const int c = tid + i * 512;
        srow[c] = (x[i] - mu) * rstd * lng[c] + lnb[c];
    }
    __syncthreads();

    // ---- logits: (d, ks) = (128, 4); 384 k-iters each
    const int d  = tid & 127;
    const int ks = tid >> 7;                  // 0..3
    const int dd = d < 100 ? d : 99;
    float acc = (ks == 0) ? b2[dd] : 0.0f;
    const float* hr  = srow + ks * 384;
    const float* w2p = W2 + (size_t)(ks * 384) * 100 + dd;
    #pragma unroll 8
    for (int k = 0; k < 384; ++k)
        acc += hr[k] * w2p[(size_t)k * 100];
    if (ks) redl[(ks - 1) * 128 + d] = acc;
    __syncthreads();
    if (ks == 0) {
        const float tot = acc + redl[d] + redl[128 + d] + redl[256 + d];
        slog[d] = (d < 100) ? tot : -INFINITY;
    }
    __syncthreads();

    // ---- wave 0: softmax max-prob + argmax (first-max tie-break)
    if (wv == 0) {
        const float v0 = slog[lane], v1 = slog[lane + 64];
        float bv; int bi;
        if (v0 >= v1) { bv = v0; bi = lane; } else { bv = v1; bi = lane + 64; }
        #pragma unroll
        for (int o = 1; o < 64; o <<= 1) {
            const float vo = __shfl_xor(bv, o, 64);
            const int   io = __shfl_xor(bi, o, 64);
            if (vo > bv || (vo == bv && io < bi)) { bv = vo; bi = io; }
        }
        float e = expf(v0 - bv) + expf(v1 - bv);   // exp(-inf)=0 pads
        #pragma unroll
        for (int o = 32; o > 0; o >>= 1) e += __shfl_xor(e, o, 64);
        if (lane == 0) {
            out[262144 + row] = 1.0f / e;          // VG_scores
            out[262656 + row] = (float)bi;         // VG_scores_index
            ssel = bi;
        }
    }
    __syncthreads();

    // ---- block 511: sel-derived constants u / Gw / Bw
    if (row == 511) {
        const int sel = ssel;
        float gw = 0.f, bw = 0.f;
        #pragma unroll
        for (int c = tid; c < 1536; c += 512) {
            const float wv2 = W2[(size_t)c * 100 + sel];
            const float uu = lng[c] * wv2;
            u[c] = uu;
            gw += uu;
            bw += lnb[c] * wv2;
        }
        #pragma unroll
        for (int o = 32; o > 0; o >>= 1) {
            gw += __shfl_xor(gw, o, 64);
            bw += __shfl_xor(bw, o, 64);
        }
        if (lane == 0) { red16[wv] = gw; red16[8 + wv] = bw; }
        __syncthreads();
        if (tid == 0) {
            float G = 0.f, B = 0.f;
            #pragma unroll
            for (int i = 0; i < 8; ++i) { G += red16[i]; B += red16[8 + i]; }
            gwbw[0] = G;
            gwbw[1] = B + b2[sel];
        }
    }
}

// ---------------------------------------------------------------------------
// gemm1p: [32768,768]x[768,1536], 128x128 tile, BK=64, 12 K-tiles.
// K-loop verbatim r28 (745 TF, 148 unified regs, 3 waves/SIMD). Epilogue:
// in-register nt-sum + 16-lane shfl_xor tree per row (C/D col=l15,
// row=q*4+r), 3KB sred combine — replaces the 33KB LDS act round-trip.
// ---------------------------------------------------------------------------
__global__ __launch_bounds__(256) void gemm1p(
        const bf16_t* __restrict__ A, const bf16_t* __restrict__ Bt,
        const float* __restrict__ bias, const float* __restrict__ u,
        float* __restrict__ pS1, float* __restrict__ pS2,
        float* __restrict__ pD) {
    constexpr int K = 768;
    __shared__ alignas(16) char smem[36864];   // sA 16KB | sB 16KB | sred 3KB
    bf16_t* sA = (bf16_t*)smem;                // [128][64] bf16, swizzled
    bf16_t* sB = (bf16_t*)(smem + 16384);      // [128][64] bf16, swizzled

    // XCD-aware remap: 12 n-tiles of one m-tile land on one XCD
    const int linear = blockIdx.x + gridDim.x * blockIdx.y;
    const int xcd  = linear & 7;
    const int slot = linear >> 3;
    const int bx = slot % gridDim.x;
    const int by = (slot / gridDim.x) * 8 + xcd;

    const int tid  = threadIdx.x;
    const int lane = tid & 63;
    const int wave = tid >> 6;
    const int wr = wave >> 1, wc = wave & 1;
    const int m0 = by * 128;
    const int n0 = bx * 128;
    const int q  = lane >> 4;
    const int l15 = lane & 15;

    // ---- staging bases (A and B identical structure; 8 granules/row,
    //      swizzle gcol = col ^ (row&7); LDS dest linear, wave-uniform base)
    const bf16_t* gA[4]; bf16_t* lA[4];
    const bf16_t* gB[4]; bf16_t* lB[4];
    #pragma unroll
    for (int c = 0; c < 4; ++c) {
        const int s    = c * 256 + tid;
        const int row  = s >> 3;
        const int col  = s & 7;
        const int gcol = col ^ (row & 7);
        gA[c] = A  + (size_t)(m0 + row) * K + gcol * 8;
        lA[c] = sA + (c * 256 + wave * 64) * 8;
        gB[c] = Bt + (size_t)(n0 + row) * K + gcol * 8;
        lB[c] = sB + (c * 256 + wave * 64) * 8;
    }
    // ---- read bases (K-step invariant); row&7 == lane&7 for both
    const bf16_t* rA[4]; const bf16_t* rB[4];
    #pragma unroll
    for (int t4 = 0; t4 < 4; ++t4) {
        rA[t4] = sA + (wr * 64 + t4 * 16 + l15) * 64;
        rB[t4] = sB + (wc * 64 + t4 * 16 + l15) * 64;
    }
    const int c0 = ((q)     ^ (lane & 7)) * 8;   // ks=0 fragment offset
    const int c1 = ((4 + q) ^ (lane & 7)) * 8;   // ks=1 fragment offset

    floatx4 acc[4][4] = {};

    #pragma unroll
    for (int kt = 0; kt < 12; ++kt) {
        const int k0 = kt * 64;
        __syncthreads();   // prev compute done before LDS overwrite
        #pragma unroll
        for (int c = 0; c < 4; ++c) gl_lds16(gB[c] + k0, lB[c]);
        #pragma unroll
        for (int c = 0; c < 4; ++c) gl_lds16(gA[c] + k0, lA[c]);
        __syncthreads();   // drain DMA, then barrier

        #pragma unroll
        for (int ks = 0; ks < 2; ++ks) {
            const int co = ks ? c1 : c0;
            bf16x8 af[4], bfr[4];
            #pragma unroll
            for (int t4 = 0; t4 < 4; ++t4) {
                af[t4]  = *(const bf16x8*)(rA[t4] + co);
                bfr[t4] = *(const bf16x8*)(rB[t4] + co);
            }
            #pragma unroll
            for (int mt = 0; mt < 4; ++mt)
                #pragma unroll
                for (int nt = 0; nt < 4; ++nt)
                    acc[mt][nt] = __builtin_amdgcn_mfma_f32_16x16x32_bf16(
                        af[mt], bfr[nt], acc[mt][nt], 0, 0, 0);
        }
    }

    // ---- stats epilogue: in-register reduction. C/D: col=l15, row=q*4+r.
    __syncthreads();                       // all tile ds_reads done
    float* sred = (float*)smem;            // [128][2][3] fp32 = 3072 B

    float u4[4], bias4[4];
    #pragma unroll
    for (int nt = 0; nt < 4; ++nt) {
        u4[nt]    = u[n0 + wc * 64 + nt * 16 + l15];
        bias4[nt] = bias[n0 + wc * 64 + nt * 16 + l15];
    }

    #pragma unroll
    for (int mt = 0; mt < 4; ++mt)
        #pragma unroll
        for (int r = 0; r < 4; ++r) {
            float s1 = 0.f, s2 = 0.f, dd = 0.f;
            #pragma unroll
            for (int nt = 0; nt < 4; ++nt) {
                // identical per-term chain to old epilogue: bf16-round the
                // activation before accumulating
                const float v = (float)(bf16_t)gelu_fast(acc[mt][nt][r] + bias4[nt]);
                s1 += v; s2 += v * v; dd += v * u4[nt];
            }
            // reduce across the 16 lanes of this q-group (cols mod 16)
            #pragma unroll
            for (int o = 1; o < 16; o <<= 1) {
                s1 += __shfl_xor(s1, o, 64);
                s2 += __shfl_xor(s2, o, 64);
                dd += __shfl_xor(dd, o, 64);
            }
            if (l15 == 0) {
                const int rowl = wr * 64 + mt * 16 + q * 4 + r;
                float* p = sred + (rowl * 2 + wc) * 3;
                p[0] = s1; p[1] = s2; p[2] = dd;
            }
        }
    __syncthreads();
    if (tid < 128) {
        const float* p0 = sred + (tid * 2 + 0) * 3;   // wc=0 half (cols 0-63)
        const float* p1 = sred + (tid * 2 + 1) * 3;   // wc=1 half (cols 64-127)
        const size_t idx = (size_t)bx * 32768 + (m0 + tid);
        pS1[idx] = p0[0] + p1[0];
        pS2[idx] = p0[1] + p1[1];
        pD[idx]  = p0[2] + p1[2];
    }
}

// ---------------------------------------------------------------------------
// out_scores: out[t*8+k] = rstd*(D - mu*Gw) + Bw   (32768 threads)
// ---------------------------------------------------------------------------
__global__ __launch_bounds__(256) void out_scores(
        const float* __restrict__ pS1, const float* __restrict__ pS2,
        const float* __restrict__ pD,  const float* __restrict__ gwbw,
        float* __restrict__ out) {
    const int t = blockIdx.x * 256 + threadIdx.x;   // 32768 exactly
    float s1 = 0.f, s2 = 0.f, d = 0.f;
    #pragma unroll
    for (int nt = 0; nt < 12; ++nt) {
        const size_t idx = (size_t)nt * 32768 + t;
        s1 += pS1[idx]; s2 += pS2[idx]; d += pD[idx];
    }
    const float mu   = s1 * (1.0f / 1536.0f);
    const float var  = s2 * (1.0f / 1536.0f) - mu * mu;
    const float rstd = rsqrtf(var + 1e-12f);
    const float v = rstd * (d - mu * gwbw[0]) + gwbw[1];
    const float4 f = make_float4(v, v, v, v);
    float4* o = (float4*)(out + (size_t)t * 8);
    o[0] = f; o[1] = f;
}

// ---------------------------------------------------------------------------
extern "C" void kernel_launch(void* const* d_in, const int* in_sizes, int n_in,
                              void* d_out, int out_size, void* d_ws, size_t ws_size,
                              hipStream_t stream) {
    const float* E   = (const float*)d_in[0];
    const float* W1  = (const float*)d_in[1];
    const float* b1  = (const float*)d_in[2];
    const float* lng = (const float*)d_in[3];
    const float* lnb = (const float*)d_in[4];
    const float* W2  = (const float*)d_in[5];
    const float* b2  = (const float*)d_in[6];
    float* out = (float*)d_out;

    char* w = (char*)d_ws;
    auto carve = [&](size_t bytes) {
        void* p = (void*)w;
        w += (bytes + 255) & ~(size_t)255;
        return p;
    };
    bf16_t* W1t   = (bf16_t*)carve((size_t)1536 * 768 * 2);    //  2.4 MB
    bf16_t* Ebf   = (bf16_t*)carve((size_t)32768 * 768 * 2);   // 50.3 MB
    float*  u     = (float*)carve(1536 * 4);
    float*  gwbw  = (float*)carve(256);
    // Union region: hpart (12.6 MB, written by prep_duo, dead after
    // own_lnlog) overlaps pS1/pS2/pD (4.7 MB, first written by gemm1p,
    // which runs after own_lnlog) — disjoint lifetimes.
    char*   unionr = (char*)carve((size_t)4 * 512 * 1536 * 4); // 12.6 MB
    float*  hpart = (float*)unionr;
    float*  pS1   = (float*)unionr;
    float*  pS2   = (float*)(unionr + (size_t)12 * 32768 * 4);
    float*  pD    = (float*)(unionr + (size_t)24 * 32768 * 4);

    // 1) prep: W1 transpose + own-row k-partials + E->bf16 (fused grid)
    prep_duo<<<12832, 256, 0, stream>>>(E, W1, W1t, hpart, Ebf);
    // 2) own rows: gelu+LN+logits+softmax/argmax; block 511 -> u/Gw/Bw
    own_lnlog<<<512, 512, 0, stream>>>(hpart, b1, lng, lnb, W2, b2,
                                       out, u, gwbw);
    // 3) fused GEMM, both operands bf16 via async DMA
    gemm1p<<<dim3(12, 256), 256, 0, stream>>>(Ebf, W1t, b1, u, pS1, pS2, pD);
    // 4) combine partials -> output 0
    out_scores<<<128, 256, 0, stream>>>(pS1, pS2, pD, gwbw, out);
}

// Round 18
// 322.866 us; speedup vs baseline: 1.1053x; 1.0001x over previous
//
#include <hip/hip_runtime.h>
#include <hip/hip_bf16.h>
#include <math.h>

// ---------------------------------------------------------------------------
// ModelFC_49134425866355 on MI355X (gfx950)
//
// out0[row] = dot(LN(gelu(E@W1+b1))*g+b, W2[:,sel]) + b2[sel]
//           = rstd*(D - mu*Gw) + Bw     (algebraic LN+GEMV fusion)
//
// r34 = r28 champion (301.9us) RESTORED + cvt grid consolidation.
// r32's in-register shuffle epilogue regressed (+19us): bank conflicts
// 3.1M->0 but 192 serially-dependent shfl_xor ops beat the hidden LDS
// round-trip. Epilogue reverted to the measured-good LDS form.
// Change this round: cvt phase 12288 tiny blocks -> 2048 blocks x 6
// grid-stride iters (exact same (block,thread)->element map via
// cb + i*2048; element-identical). Amortizes CP block-dispatch overhead.
// 4 kernels: prep_duo(+cvt) | own_lnlog(+fin) | gemm1p | out_scores.
// ---------------------------------------------------------------------------

typedef __bf16 bf16_t;
typedef __bf16  bf16x2  __attribute__((ext_vector_type(2)));
typedef __bf16  bf16x8  __attribute__((ext_vector_type(8)));
typedef float   floatx4 __attribute__((ext_vector_type(4)));

__device__ __forceinline__ float gelu_exact(float x) {
    return 0.5f * x * (1.0f + erff(x * 0.7071067811865475f));
}
// tanh-form gelu via sigmoid; |err|<~1e-3, below bf16 rounding of bulk path.
__device__ __forceinline__ float gelu_fast(float x) {
    const float z = x * (1.0f + 0.044715f * x * x);
    return __fdividef(x, 1.0f + __expf(-1.5957691216f * z));
}

// async global->LDS, 16B per lane; lds base wave-uniform (HW adds lane*16).
// OFFSET ARG STAYS 0 — nonzero immediate is unverified and broke round 5.
__device__ __forceinline__ void gl_lds16(const void* g, void* l) {
    __builtin_amdgcn_global_load_lds(
        (const __attribute__((address_space(1))) void*)g,
        (__attribute__((address_space(3))) void*)l, 16, 0, 0);
}

// ---------------------------------------------------------------------------
// prep_duo: [0,288) tr_w1 | [288,544) own_h (full-row) | [544,2592) cvt
// cvt blocks grid-stride 6 chunks each (2048 x 256 x 8 x 6 = 25,165,824).
// ---------------------------------------------------------------------------
__global__ __launch_bounds__(256) void prep_duo(
        const float* __restrict__ E, const float* __restrict__ W1,
        bf16_t* __restrict__ W1t, float* __restrict__ hpart,
        bf16_t* __restrict__ Ebf) {
    __shared__ alignas(16) char smemc[16640];   // max(sT 64x65 fp32, sE 6KB)
    const int bid = blockIdx.x;
    const int tid = threadIdx.x;

    if (bid >= 544) {                   // ---- E -> bf16 (25,165,824 elems)
        const int cb = bid - 544;       // 0..2047
        #pragma unroll
        for (int i = 0; i < 6; ++i) {
            const size_t base = (((size_t)(cb + i * 2048)) * 256 + tid) * 8;
            const float4 v0 = *(const float4*)(E + base);
            const float4 v1 = *(const float4*)(E + base + 4);
            bf16x8 o;
            o[0] = (bf16_t)v0.x; o[1] = (bf16_t)v0.y;
            o[2] = (bf16_t)v0.z; o[3] = (bf16_t)v0.w;
            o[4] = (bf16_t)v1.x; o[5] = (bf16_t)v1.y;
            o[6] = (bf16_t)v1.z; o[7] = (bf16_t)v1.w;
            *(bf16x8*)(Ebf + base) = o;
        }
        return;
    }

    if (bid < 288) {                    // ---- tr_w1: 64x64 LDS-tiled transpose
        float* sT = (float*)smemc;      // [64][65]
        const int bk = bid % 12, bn = bid / 12;
        const int k0 = bk * 64, n0 = bn * 64;
        #pragma unroll
        for (int i = 0; i < 16; ++i) {
            const int idx = tid + i * 256;
            const int kk = idx >> 6, nn = idx & 63;
            sT[kk * 65 + nn] = W1[(size_t)(k0 + kk) * 1536 + n0 + nn];
        }
        __syncthreads();
        // vectorized bf16x2 stores: idx covers (nn, kk-pair)
        #pragma unroll
        for (int i = 0; i < 8; ++i) {
            const int idx = tid + i * 256;   // 0..2047
            const int nn = idx >> 5;         // 0..63
            const int kp = (idx & 31) * 2;   // 0,2,..,62
            bf16x2 v;
            v[0] = (bf16_t)sT[kp * 65 + nn];
            v[1] = (bf16_t)sT[(kp + 1) * 65 + nn];
            *(bf16x2*)(W1t + (size_t)(n0 + nn) * 768 + k0 + kp) = v;
        }
    } else {                            // ---- own_h: hpart[kq][512][1536]
        // 256 blocks: (a, kq); each covers ALL 1536 cols (6 cols/thread).
        // Per-column k-order identical -> hpart bit-identical.
        float* sE = (float*)smemc;      // [8][192]
        const int b  = bid - 288;       // 0..255
        const int a  = b & 63;
        const int kq = b >> 6;          // 0..3

        const float* Ebase = E + (size_t)(520 * a) * 768 + kq * 192;
        for (int idx = tid; idx < 1536; idx += 256) {
            const int row = idx / 192, i = idx - row * 192;
            sE[idx] = Ebase[(size_t)row * 768 + i];
        }
        __syncthreads();

        const int c0 = tid * 2;         // 0..510
        const float* w1p = W1 + (size_t)(kq * 192) * 1536 + c0;
        float ax0[8] = {}, ay0[8] = {};
        float ax1[8] = {}, ay1[8] = {};
        float ax2[8] = {}, ay2[8] = {};
        for (int k = 0; k < 192; ++k) {
            const float* wk = w1p + (size_t)k * 1536;
            const float2 w0 = *(const float2*)(wk);
            const float2 w1v = *(const float2*)(wk + 512);
            const float2 w2v = *(const float2*)(wk + 1024);
            #pragma unroll
            for (int j = 0; j < 8; ++j) {
                const float e = sE[j * 192 + k];   // LDS broadcast, shared x3
                ax0[j] += w0.x * e;  ay0[j] += w0.y * e;
                ax1[j] += w1v.x * e; ay1[j] += w1v.y * e;
                ax2[j] += w2v.x * e; ay2[j] += w2v.y * e;
            }
        }
        #pragma unroll
        for (int j = 0; j < 8; ++j) {
            float* hp = hpart + (size_t)(kq * 512 + a * 8 + j) * 1536 + c0;
            *(float2*)(hp)        = make_float2(ax0[j], ay0[j]);
            *(float2*)(hp + 512)  = make_float2(ax1[j], ay1[j]);
            *(float2*)(hp + 1024) = make_float2(ax2[j], ay2[j]);
        }
    }
}

// ---------------------------------------------------------------------------
// own_lnlog: per row (512 blocks x 512 threads). (verbatim r22/r28)
// ---------------------------------------------------------------------------
__global__ __launch_bounds__(512) void own_lnlog(
        const float* __restrict__ hpart, const float* __restrict__ b1,
        const float* __restrict__ lng,  const float* __restrict__ lnb,
        const float* __restrict__ W2,   const float* __restrict__ b2,
        float* __restrict__ out, float* __restrict__ u,
        float* __restrict__ gwbw) {
    __shared__ float srow[1536];
    __shared__ float red16[16];
    __shared__ float redl[384];
    __shared__ float slog[128];
    __shared__ int   ssel;
    const int row = blockIdx.x, tid = threadIdx.x;
    const int lane = tid & 63, wv = tid >> 6;   // wv 0..7

    // ---- gelu(sum of partials + b1), 3 cols/thread
    float x[3];
    #pragma unroll
    for (int i = 0; i < 3; ++i) {
        const int c = tid + i * 512;
        x[i] = gelu_exact(hpart[(size_t)row * 1536 + c]
                        + hpart[(size_t)(512 + row) * 1536 + c]
                        + hpart[(size_t)(1024 + row) * 1536 + c]
                        + hpart[(size_t)(1536 + row) * 1536 + c] + b1[c]);
    }
    float s = x[0] + x[1] + x[2];
    #pragma unroll
    for (int o = 32; o > 0; o >>= 1) s += __shfl_xor(s, o, 64);
    if (lane == 0) red16[wv] = s;
    __syncthreads();
    float mu = 0.f;
    #pragma unroll
    for (int i = 0; i < 8; ++i) mu += red16[i];
    mu *= (1.0f / 1536.0f);

    float s2 = 0.f;
    #pragma unroll
    for (int i = 0; i < 3; ++i) { float d = x[i] - mu; s2 += d * d; }
    #pragma unroll
    for (int o = 32; o > 0; o >>= 1) s2 += __shfl_xor(s2, o, 64);
    if (lane == 0) red16[8 + wv] = s2;
    __syncthreads();
    float v2 = 0.f;
    #pragma unroll
    for (int i = 0; i < 8; ++i) v2 += red16[8 + i];
    const float rstd = rsqrtf(v2 * (1.0f / 1536.0f) + 1e-12f);

    #pragma unroll
    for (int i = 0; i < 3; ++i) {
        const int c = tid + i * 512;
        srow[c] = (x[i] - mu) * rstd * lng[c] + lnb[c];
    }
    __syncthreads();

    // ---- logits: (d, ks) = (128, 4); 384 k-iters each
    const int d  = tid & 127;
    const int ks = tid >> 7;                  // 0..3
    const int dd = d < 100 ? d : 99;
    float acc = (ks == 0) ? b2[dd] : 0.0f;
    const float* hr  = srow + ks * 384;
    const float* w2p = W2 + (size_t)(ks * 384) * 100 + dd;
    #pragma unroll 8
    for (int k = 0; k < 384; ++k)
        acc += hr[k] * w2p[(size_t)k * 100];
    if (ks) redl[(ks - 1) * 128 + d] = acc;
    __syncthreads();
    if (ks == 0) {
        const float tot = acc + redl[d] + redl[128 + d] + redl[256 + d];
        slog[d] = (d < 100) ? tot : -INFINITY;
    }
    __syncthreads();

    // ---- wave 0: softmax max-prob + argmax (first-max tie-break)
    if (wv == 0) {
        const float v0 = slog[lane], v1 = slog[lane + 64];
        float bv; int bi;
        if (v0 >= v1) { bv = v0; bi = lane; } else { bv = v1; bi = lane + 64; }
        #pragma unroll
        for (int o = 1; o < 64; o <<= 1) {
            const float vo = __shfl_xor(bv, o, 64);
            const int   io = __shfl_xor(bi, o, 64);
            if (vo > bv || (vo == bv && io < bi)) { bv = vo; bi = io; }
        }
        float e = expf(v0 - bv) + expf(v1 - bv);   // exp(-inf)=0 pads
        #pragma unroll
        for (int o = 32; o > 0; o >>= 1) e += __shfl_xor(e, o, 64);
        if (lane == 0) {
            out[262144 + row] = 1.0f / e;          // VG_scores
            out[262656 + row] = (float)bi;         // VG_scores_index
            ssel = bi;
        }
    }
    __syncthreads();

    // ---- block 511: sel-derived constants u / Gw / Bw
    if (row == 511) {
        const int sel = ssel;
        float gw = 0.f, bw = 0.f;
        #pragma unroll
        for (int c = tid; c < 1536; c += 512) {
            const float wv2 = W2[(size_t)c * 100 + sel];
            const float uu = lng[c] * wv2;
            u[c] = uu;
            gw += uu;
            bw += lnb[c] * wv2;
        }
        #pragma unroll
        for (int o = 32; o > 0; o >>= 1) {
            gw += __shfl_xor(gw, o, 64);
            bw += __shfl_xor(bw, o, 64);
        }
        if (lane == 0) { red16[wv] = gw; red16[8 + wv] = bw; }
        __syncthreads();
        if (tid == 0) {
            float G = 0.f, B = 0.f;
            #pragma unroll
            for (int i = 0; i < 8; ++i) { G += red16[i]; B += red16[8 + i]; }
            gwbw[0] = G;
            gwbw[1] = B + b2[sel];
        }
    }
}

// ---------------------------------------------------------------------------
// gemm1p: [32768,768]x[768,1536], 128x128 tile, BK=64, 12 K-tiles.
// VERBATIM r28 (measured 102us, MfmaUtil 34, 84 VGPR + 64 AGPR, 3 w/SIMD).
// LDS round-trip stats epilogue — measured FASTER than both the 2-M-tile
// variant (reg pressure) and the shfl-tree epilogue (serial cross-lane).
// ---------------------------------------------------------------------------
__global__ __launch_bounds__(256) void gemm1p(
        const bf16_t* __restrict__ A, const bf16_t* __restrict__ Bt,
        const float* __restrict__ bias, const float* __restrict__ u,
        float* __restrict__ pS1, float* __restrict__ pS2,
        float* __restrict__ pD) {
    constexpr int K = 768;
    __shared__ alignas(16) char smem[36864];   // sA 16KB | sB 16KB; epi 36KB
    bf16_t* sA = (bf16_t*)smem;                // [128][64] bf16, swizzled
    bf16_t* sB = (bf16_t*)(smem + 16384);      // [128][64] bf16, swizzled

    // XCD-aware remap: 12 n-tiles of one m-tile land on one XCD
    const int linear = blockIdx.x + gridDim.x * blockIdx.y;
    const int xcd  = linear & 7;
    const int slot = linear >> 3;
    const int bx = slot % gridDim.x;
    const int by = (slot / gridDim.x) * 8 + xcd;

    const int tid  = threadIdx.x;
    const int lane = tid & 63;
    const int wave = tid >> 6;
    const int wr = wave >> 1, wc = wave & 1;
    const int m0 = by * 128;
    const int n0 = bx * 128;
    const int q  = lane >> 4;
    const int l15 = lane & 15;

    // ---- staging bases (A and B identical structure; 8 granules/row,
    //      swizzle gcol = col ^ (row&7); LDS dest linear, wave-uniform base)
    const bf16_t* gA[4]; bf16_t* lA[4];
    const bf16_t* gB[4]; bf16_t* lB[4];
    #pragma unroll
    for (int c = 0; c < 4; ++c) {
        const int s    = c * 256 + tid;
        const int row  = s >> 3;
        const int col  = s & 7;
        const int gcol = col ^ (row & 7);
        gA[c] = A  + (size_t)(m0 + row) * K + gcol * 8;
        lA[c] = sA + (c * 256 + wave * 64) * 8;
        gB[c] = Bt + (size_t)(n0 + row) * K + gcol * 8;
        lB[c] = sB + (c * 256 + wave * 64) * 8;
    }
    // ---- read bases (K-step invariant); row&7 == lane&7 for both
    const bf16_t* rA[4]; const bf16_t* rB[4];
    #pragma unroll
    for (int t4 = 0; t4 < 4; ++t4) {
        rA[t4] = sA + (wr * 64 + t4 * 16 + l15) * 64;
        rB[t4] = sB + (wc * 64 + t4 * 16 + l15) * 64;
    }
    const int c0 = ((q)     ^ (lane & 7)) * 8;   // ks=0 fragment offset
    const int c1 = ((4 + q) ^ (lane & 7)) * 8;   // ks=1 fragment offset

    floatx4 acc[4][4] = {};

    #pragma unroll
    for (int kt = 0; kt < 12; ++kt) {
        const int k0 = kt * 64;
        __syncthreads();   // prev compute done before LDS overwrite
        #pragma unroll
        for (int c = 0; c < 4; ++c) gl_lds16(gB[c] + k0, lB[c]);
        #pragma unroll
        for (int c = 0; c < 4; ++c) gl_lds16(gA[c] + k0, lA[c]);
        __syncthreads();   // drain DMA, then barrier

        #pragma unroll
        for (int ks = 0; ks < 2; ++ks) {
            const int co = ks ? c1 : c0;
            bf16x8 af[4], bfr[4];
            #pragma unroll
            for (int t4 = 0; t4 < 4; ++t4) {
                af[t4]  = *(const bf16x8*)(rA[t4] + co);
                bfr[t4] = *(const bf16x8*)(rB[t4] + co);
            }
            #pragma unroll
            for (int mt = 0; mt < 4; ++mt)
                #pragma unroll
                for (int nt = 0; nt < 4; ++nt)
                    acc[mt][nt] = __builtin_amdgcn_mfma_f32_16x16x32_bf16(
                        af[mt], bfr[nt], acc[mt][nt], 0, 0, 0);
        }
    }

    // ---- stats epilogue via LDS (low VGPR). C/D layout: col=l15, row=q*4+r.
    __syncthreads();                       // all tile ds_reads done
    bf16_t* sh = (bf16_t*)smem;            // [128][130] bf16 = 33280 B
    float*  su = (float*)(smem + 33280);   // u[n0..n0+127]          512 B
    float*  sp = (float*)(smem + 33792);   // [256][3] partials     3072 B

    if (tid < 128) su[tid] = u[n0 + tid];
    float bias4[4];
    #pragma unroll
    for (int nt = 0; nt < 4; ++nt) bias4[nt] = bias[n0 + wc * 64 + nt * 16 + l15];

    #pragma unroll
    for (int mt = 0; mt < 4; ++mt)
        #pragma unroll
        for (int nt = 0; nt < 4; ++nt)
            #pragma unroll
            for (int r = 0; r < 4; ++r) {
                const int rowl = wr * 64 + mt * 16 + q * 4 + r;
                const int coll = wc * 64 + nt * 16 + l15;
                sh[rowl * 130 + coll] = (bf16_t)gelu_fast(acc[mt][nt][r] + bias4[nt]);
            }
    __syncthreads();

    // phase 2: thread = (row, half); reduce 64 cols each
    {
        const int rowl = tid >> 1, half = tid & 1;
        const bf16_t* hp = sh + rowl * 130 + half * 64;
        const float*  up = su + half * 64;
        float s1 = 0.f, s2 = 0.f, dd = 0.f;
        #pragma unroll
        for (int c = 0; c < 64; ++c) {
            const float v = (float)hp[c];
            s1 += v; s2 += v * v; dd += v * up[c];
        }
        sp[tid * 3 + 0] = s1; sp[tid * 3 + 1] = s2; sp[tid * 3 + 2] = dd;
    }
    __syncthreads();
    if (tid < 128) {
        const float* p0 = sp + (2 * tid) * 3;
        const float* p1 = sp + (2 * tid + 1) * 3;
        const size_t idx = (size_t)bx * 32768 + (m0 + tid);
        pS1[idx] = p0[0] + p1[0];
        pS2[idx] = p0[1] + p1[1];
        pD[idx]  = p0[2] + p1[2];
    }
}

// ---------------------------------------------------------------------------
// out_scores: out[t*8+k] = rstd*(D - mu*Gw) + Bw   (32768 threads)
// ---------------------------------------------------------------------------
__global__ __launch_bounds__(256) void out_scores(
        const float* __restrict__ pS1, const float* __restrict__ pS2,
        const float* __restrict__ pD,  const float* __restrict__ gwbw,
        float* __restrict__ out) {
    const int t = blockIdx.x * 256 + threadIdx.x;   // 32768 exactly
    float s1 = 0.f, s2 = 0.f, d = 0.f;
    #pragma unroll
    for (int nt = 0; nt < 12; ++nt) {
        const size_t idx = (size_t)nt * 32768 + t;
        s1 += pS1[idx]; s2 += pS2[idx]; d += pD[idx];
    }
    const float mu   = s1 * (1.0f / 1536.0f);
    const float var  = s2 * (1.0f / 1536.0f) - mu * mu;
    const float rstd = rsqrtf(var + 1e-12f);
    const float v = rstd * (d - mu * gwbw[0]) + gwbw[1];
    const float4 f = make_float4(v, v, v, v);
    float4* o = (float4*)(out + (size_t)t * 8);
    o[0] = f; o[1] = f;
}

// ---------------------------------------------------------------------------
extern "C" void kernel_launch(void* const* d_in, const int* in_sizes, int n_in,
                              void* d_out, int out_size, void* d_ws, size_t ws_size,
                              hipStream_t stream) {
    const float* E   = (const float*)d_in[0];
    const float* W1  = (const float*)d_in[1];
    const float* b1  = (const float*)d_in[2];
    const float* lng = (const float*)d_in[3];
    const float* lnb = (const float*)d_in[4];
    const float* W2  = (const float*)d_in[5];
    const float* b2  = (const float*)d_in[6];
    float* out = (float*)d_out;

    char* w = (char*)d_ws;
    auto carve = [&](size_t bytes) {
        void* p = (void*)w;
        w += (bytes + 255) & ~(size_t)255;
        return p;
    };
    bf16_t* W1t   = (bf16_t*)carve((size_t)1536 * 768 * 2);    //  2.4 MB
    bf16_t* Ebf   = (bf16_t*)carve((size_t)32768 * 768 * 2);   // 50.3 MB
    float*  u     = (float*)carve(1536 * 4);
    float*  gwbw  = (float*)carve(256);
    // Union region: hpart (12.6 MB, written by prep_duo, dead after
    // own_lnlog) overlaps pS1/pS2/pD (4.7 MB, first written by gemm1p,
    // which runs after own_lnlog) — disjoint lifetimes.
    char*   unionr = (char*)carve((size_t)4 * 512 * 1536 * 4); // 12.6 MB
    float*  hpart = (float*)unionr;
    float*  pS1   = (float*)unionr;
    float*  pS2   = (float*)(unionr + (size_t)12 * 32768 * 4);
    float*  pD    = (float*)(unionr + (size_t)24 * 32768 * 4);

    // 1) prep: W1 transpose + own-row k-partials + E->bf16 (fused grid)
    prep_duo<<<2592, 256, 0, stream>>>(E, W1, W1t, hpart, Ebf);
    // 2) own rows: gelu+LN+logits+softmax/argmax; block 511 -> u/Gw/Bw
    own_lnlog<<<512, 512, 0, stream>>>(hpart, b1, lng, lnb, W2, b2,
                                       out, u, gwbw);
    // 3) fused GEMM, both operands bf16 via async DMA
    gemm1p<<<dim3(12, 256), 256, 0, stream>>>(Ebf, W1t, b1, u, pS1, pS2, pD);
    // 4) combine partials -> output 0
    out_scores<<<128, 256, 0, stream>>>(pS1, pS2, pD, gwbw, out);
}

// Round 19
// 299.836 us; speedup vs baseline: 1.1902x; 1.0768x over previous
//
#include <hip/hip_runtime.h>
#include <hip/hip_bf16.h>
#include <math.h>

// ---------------------------------------------------------------------------
// ModelFC_49134425866355 on MI355X (gfx950)
//
// out0[row] = dot(LN(gelu(E@W1+b1))*g+b, W2[:,sel]) + b2[sel]
//           = rstd*(D - mu*Gw) + Bw     (algebraic LN+GEMV fusion)
//
// r36 = r28 champion RESTORED VERBATIM (301.9us measured round 15).
// Deviations all regressed with identified mechanisms:
//  - r24 rider-merge: +15 (gemm MfmaUtil dilution 34->27.5)
//  - r30 2-M-tile gemm: +55 (unified-file 268 regs -> 1 wave/SIMD)
//  - r32 shfl-tree epilogue: +21 (192 serial cross-lane ops; conflicts
//    were hidden under TLP anyway)
//  - r34 cvt 2048x6 grid-stride: +20 (lost cvt/own_h interleave + tail)
// Non-gemm time agreed within 2us across r28/r32 (199.6/201.8) -> machine
// noise is small; this config is the verified champion.
// 4 kernels: prep_duo(+cvt) | own_lnlog(+fin) | gemm1p | out_scores.
// ---------------------------------------------------------------------------

typedef __bf16 bf16_t;
typedef __bf16  bf16x2  __attribute__((ext_vector_type(2)));
typedef __bf16  bf16x8  __attribute__((ext_vector_type(8)));
typedef float   floatx4 __attribute__((ext_vector_type(4)));

__device__ __forceinline__ float gelu_exact(float x) {
    return 0.5f * x * (1.0f + erff(x * 0.7071067811865475f));
}
// tanh-form gelu via sigmoid; |err|<~1e-3, below bf16 rounding of bulk path.
__device__ __forceinline__ float gelu_fast(float x) {
    const float z = x * (1.0f + 0.044715f * x * x);
    return __fdividef(x, 1.0f + __expf(-1.5957691216f * z));
}

// async global->LDS, 16B per lane; lds base wave-uniform (HW adds lane*16).
// OFFSET ARG STAYS 0 — nonzero immediate is unverified and broke round 5.
__device__ __forceinline__ void gl_lds16(const void* g, void* l) {
    __builtin_amdgcn_global_load_lds(
        (const __attribute__((address_space(1))) void*)g,
        (__attribute__((address_space(3))) void*)l, 16, 0, 0);
}

// ---------------------------------------------------------------------------
// prep_duo: [0,288) tr_w1 | [288,544) own_h (full-row) | [544,12832) cvt
// ---------------------------------------------------------------------------
__global__ __launch_bounds__(256) void prep_duo(
        const float* __restrict__ E, const float* __restrict__ W1,
        bf16_t* __restrict__ W1t, float* __restrict__ hpart,
        bf16_t* __restrict__ Ebf) {
    __shared__ alignas(16) char smemc[16640];   // max(sT 64x65 fp32, sE 6KB)
    const int bid = blockIdx.x;
    const int tid = threadIdx.x;

    if (bid >= 544) {                   // ---- E -> bf16 (25,165,824 elems)
        const int cb = bid - 544;       // 0..12287
        const size_t base = ((size_t)cb * 256 + tid) * 8;
        const float4 v0 = *(const float4*)(E + base);
        const float4 v1 = *(const float4*)(E + base + 4);
        bf16x8 o;
        o[0] = (bf16_t)v0.x; o[1] = (bf16_t)v0.y;
        o[2] = (bf16_t)v0.z; o[3] = (bf16_t)v0.w;
        o[4] = (bf16_t)v1.x; o[5] = (bf16_t)v1.y;
        o[6] = (bf16_t)v1.z; o[7] = (bf16_t)v1.w;
        *(bf16x8*)(Ebf + base) = o;
        return;
    }

    if (bid < 288) {                    // ---- tr_w1: 64x64 LDS-tiled transpose
        float* sT = (float*)smemc;      // [64][65]
        const int bk = bid % 12, bn = bid / 12;
        const int k0 = bk * 64, n0 = bn * 64;
        #pragma unroll
        for (int i = 0; i < 16; ++i) {
            const int idx = tid + i * 256;
            const int kk = idx >> 6, nn = idx & 63;
            sT[kk * 65 + nn] = W1[(size_t)(k0 + kk) * 1536 + n0 + nn];
        }
        __syncthreads();
        // vectorized bf16x2 stores: idx covers (nn, kk-pair)
        #pragma unroll
        for (int i = 0; i < 8; ++i) {
            const int idx = tid + i * 256;   // 0..2047
            const int nn = idx >> 5;         // 0..63
            const int kp = (idx & 31) * 2;   // 0,2,..,62
            bf16x2 v;
            v[0] = (bf16_t)sT[kp * 65 + nn];
            v[1] = (bf16_t)sT[(kp + 1) * 65 + nn];
            *(bf16x2*)(W1t + (size_t)(n0 + nn) * 768 + k0 + kp) = v;
        }
    } else {                            // ---- own_h: hpart[kq][512][1536]
        // 256 blocks: (a, kq); each covers ALL 1536 cols (6 cols/thread).
        // Per-column k-order identical -> hpart bit-identical.
        float* sE = (float*)smemc;      // [8][192]
        const int b  = bid - 288;       // 0..255
        const int a  = b & 63;
        const int kq = b >> 6;          // 0..3

        const float* Ebase = E + (size_t)(520 * a) * 768 + kq * 192;
        for (int idx = tid; idx < 1536; idx += 256) {
            const int row = idx / 192, i = idx - row * 192;
            sE[idx] = Ebase[(size_t)row * 768 + i];
        }
        __syncthreads();

        const int c0 = tid * 2;         // 0..510
        const float* w1p = W1 + (size_t)(kq * 192) * 1536 + c0;
        float ax0[8] = {}, ay0[8] = {};
        float ax1[8] = {}, ay1[8] = {};
        float ax2[8] = {}, ay2[8] = {};
        for (int k = 0; k < 192; ++k) {
            const float* wk = w1p + (size_t)k * 1536;
            const float2 w0 = *(const float2*)(wk);
            const float2 w1v = *(const float2*)(wk + 512);
            const float2 w2v = *(const float2*)(wk + 1024);
            #pragma unroll
            for (int j = 0; j < 8; ++j) {
                const float e = sE[j * 192 + k];   // LDS broadcast, shared x3
                ax0[j] += w0.x * e;  ay0[j] += w0.y * e;
                ax1[j] += w1v.x * e; ay1[j] += w1v.y * e;
                ax2[j] += w2v.x * e; ay2[j] += w2v.y * e;
            }
        }
        #pragma unroll
        for (int j = 0; j < 8; ++j) {
            float* hp = hpart + (size_t)(kq * 512 + a * 8 + j) * 1536 + c0;
            *(float2*)(hp)        = make_float2(ax0[j], ay0[j]);
            *(float2*)(hp + 512)  = make_float2(ax1[j], ay1[j]);
            *(float2*)(hp + 1024) = make_float2(ax2[j], ay2[j]);
        }
    }
}

// ---------------------------------------------------------------------------
// own_lnlog: per row (512 blocks x 512 threads). (verbatim r22/r28)
// ---------------------------------------------------------------------------
__global__ __launch_bounds__(512) void own_lnlog(
        const float* __restrict__ hpart, const float* __restrict__ b1,
        const float* __restrict__ lng,  const float* __restrict__ lnb,
        const float* __restrict__ W2,   const float* __restrict__ b2,
        float* __restrict__ out, float* __restrict__ u,
        float* __restrict__ gwbw) {
    __shared__ float srow[1536];
    __shared__ float red16[16];
    __shared__ float redl[384];
    __shared__ float slog[128];
    __shared__ int   ssel;
    const int row = blockIdx.x, tid = threadIdx.x;
    const int lane = tid & 63, wv = tid >> 6;   // wv 0..7

    // ---- gelu(sum of partials + b1), 3 cols/thread
    float x[3];
    #pragma unroll
    for (int i = 0; i < 3; ++i) {
        const int c = tid + i * 512;
        x[i] = gelu_exact(hpart[(size_t)row * 1536 + c]
                        + hpart[(size_t)(512 + row) * 1536 + c]
                        + hpart[(size_t)(1024 + row) * 1536 + c]
                        + hpart[(size_t)(1536 + row) * 1536 + c] + b1[c]);
    }
    float s = x[0] + x[1] + x[2];
    #pragma unroll
    for (int o = 32; o > 0; o >>= 1) s += __shfl_xor(s, o, 64);
    if (lane == 0) red16[wv] = s;
    __syncthreads();
    float mu = 0.f;
    #pragma unroll
    for (int i = 0; i < 8; ++i) mu += red16[i];
    mu *= (1.0f / 1536.0f);

    float s2 = 0.f;
    #pragma unroll
    for (int i = 0; i < 3; ++i) { float d = x[i] - mu; s2 += d * d; }
    #pragma unroll
    for (int o = 32; o > 0; o >>= 1) s2 += __shfl_xor(s2, o, 64);
    if (lane == 0) red16[8 + wv] = s2;
    __syncthreads();
    float v2 = 0.f;
    #pragma unroll
    for (int i = 0; i < 8; ++i) v2 += red16[8 + i];
    const float rstd = rsqrtf(v2 * (1.0f / 1536.0f) + 1e-12f);

    #pragma unroll
    for (int i = 0; i < 3; ++i) {
        const int c = tid + i * 512;
        srow[c] = (x[i] - mu) * rstd * lng[c] + lnb[c];
    }
    __syncthreads();

    // ---- logits: (d, ks) = (128, 4); 384 k-iters each
    const int d  = tid & 127;
    const int ks = tid >> 7;                  // 0..3
    const int dd = d < 100 ? d : 99;
    float acc = (ks == 0) ? b2[dd] : 0.0f;
    const float* hr  = srow + ks * 384;
    const float* w2p = W2 + (size_t)(ks * 384) * 100 + dd;
    #pragma unroll 8
    for (int k = 0; k < 384; ++k)
        acc += hr[k] * w2p[(size_t)k * 100];
    if (ks) redl[(ks - 1) * 128 + d] = acc;
    __syncthreads();
    if (ks == 0) {
        const float tot = acc + redl[d] + redl[128 + d] + redl[256 + d];
        slog[d] = (d < 100) ? tot : -INFINITY;
    }
    __syncthreads();

    // ---- wave 0: softmax max-prob + argmax (first-max tie-break)
    if (wv == 0) {
        const float v0 = slog[lane], v1 = slog[lane + 64];
        float bv; int bi;
        if (v0 >= v1) { bv = v0; bi = lane; } else { bv = v1; bi = lane + 64; }
        #pragma unroll
        for (int o = 1; o < 64; o <<= 1) {
            const float vo = __shfl_xor(bv, o, 64);
            const int   io = __shfl_xor(bi, o, 64);
            if (vo > bv || (vo == bv && io < bi)) { bv = vo; bi = io; }
        }
        float e = expf(v0 - bv) + expf(v1 - bv);   // exp(-inf)=0 pads
        #pragma unroll
        for (int o = 32; o > 0; o >>= 1) e += __shfl_xor(e, o, 64);
        if (lane == 0) {
            out[262144 + row] = 1.0f / e;          // VG_scores
            out[262656 + row] = (float)bi;         // VG_scores_index
            ssel = bi;
        }
    }
    __syncthreads();

    // ---- block 511: sel-derived constants u / Gw / Bw
    if (row == 511) {
        const int sel = ssel;
        float gw = 0.f, bw = 0.f;
        #pragma unroll
        for (int c = tid; c < 1536; c += 512) {
            const float wv2 = W2[(size_t)c * 100 + sel];
            const float uu = lng[c] * wv2;
            u[c] = uu;
            gw += uu;
            bw += lnb[c] * wv2;
        }
        #pragma unroll
        for (int o = 32; o > 0; o >>= 1) {
            gw += __shfl_xor(gw, o, 64);
            bw += __shfl_xor(bw, o, 64);
        }
        if (lane == 0) { red16[wv] = gw; red16[8 + wv] = bw; }
        __syncthreads();
        if (tid == 0) {
            float G = 0.f, B = 0.f;
            #pragma unroll
            for (int i = 0; i < 8; ++i) { G += red16[i]; B += red16[8 + i]; }
            gwbw[0] = G;
            gwbw[1] = B + b2[sel];
        }
    }
}

// ---------------------------------------------------------------------------
// gemm1p: [32768,768]x[768,1536], 128x128 tile, BK=64, 12 K-tiles.
// VERBATIM r28 (measured 101-103us, MfmaUtil 34, 84 VGPR + 64 AGPR,
// 3 waves/SIMD). LDS round-trip stats epilogue — measured FASTER than both
// the 2-M-tile variant (reg pressure) and shfl-tree epilogue (serial ops).
// ---------------------------------------------------------------------------
__global__ __launch_bounds__(256) void gemm1p(
        const bf16_t* __restrict__ A, const bf16_t* __restrict__ Bt,
        const float* __restrict__ bias, const float* __restrict__ u,
        float* __restrict__ pS1, float* __restrict__ pS2,
        float* __restrict__ pD) {
    constexpr int K = 768;
    __shared__ alignas(16) char smem[36864];   // sA 16KB | sB 16KB; epi 36KB
    bf16_t* sA = (bf16_t*)smem;                // [128][64] bf16, swizzled
    bf16_t* sB = (bf16_t*)(smem + 16384);      // [128][64] bf16, swizzled

    // XCD-aware remap: 12 n-tiles of one m-tile land on one XCD
    const int linear = blockIdx.x + gridDim.x * blockIdx.y;
    const int xcd  = linear & 7;
    const int slot = linear >> 3;
    const int bx = slot % gridDim.x;
    const int by = (slot / gridDim.x) * 8 + xcd;

    const int tid  = threadIdx.x;
    const int lane = tid & 63;
    const int wave = tid >> 6;
    const int wr = wave >> 1, wc = wave & 1;
    const int m0 = by * 128;
    const int n0 = bx * 128;
    const int q  = lane >> 4;
    const int l15 = lane & 15;

    // ---- staging bases (A and B identical structure; 8 granules/row,
    //      swizzle gcol = col ^ (row&7); LDS dest linear, wave-uniform base)
    const bf16_t* gA[4]; bf16_t* lA[4];
    const bf16_t* gB[4]; bf16_t* lB[4];
    #pragma unroll
    for (int c = 0; c < 4; ++c) {
        const int s    = c * 256 + tid;
        const int row  = s >> 3;
        const int col  = s & 7;
        const int gcol = col ^ (row & 7);
        gA[c] = A  + (size_t)(m0 + row) * K + gcol * 8;
        lA[c] = sA + (c * 256 + wave * 64) * 8;
        gB[c] = Bt + (size_t)(n0 + row) * K + gcol * 8;
        lB[c] = sB + (c * 256 + wave * 64) * 8;
    }
    // ---- read bases (K-step invariant); row&7 == lane&7 for both
    const bf16_t* rA[4]; const bf16_t* rB[4];
    #pragma unroll
    for (int t4 = 0; t4 < 4; ++t4) {
        rA[t4] = sA + (wr * 64 + t4 * 16 + l15) * 64;
        rB[t4] = sB + (wc * 64 + t4 * 16 + l15) * 64;
    }
    const int c0 = ((q)     ^ (lane & 7)) * 8;   // ks=0 fragment offset
    const int c1 = ((4 + q) ^ (lane & 7)) * 8;   // ks=1 fragment offset

    floatx4 acc[4][4] = {};

    #pragma unroll
    for (int kt = 0; kt < 12; ++kt) {
        const int k0 = kt * 64;
        __syncthreads();   // prev compute done before LDS overwrite
        #pragma unroll
        for (int c = 0; c < 4; ++c) gl_lds16(gB[c] + k0, lB[c]);
        #pragma unroll
        for (int c = 0; c < 4; ++c) gl_lds16(gA[c] + k0, lA[c]);
        __syncthreads();   // drain DMA, then barrier

        #pragma unroll
        for (int ks = 0; ks < 2; ++ks) {
            const int co = ks ? c1 : c0;
            bf16x8 af[4], bfr[4];
            #pragma unroll
            for (int t4 = 0; t4 < 4; ++t4) {
                af[t4]  = *(const bf16x8*)(rA[t4] + co);
                bfr[t4] = *(const bf16x8*)(rB[t4] + co);
            }
            #pragma unroll
            for (int mt = 0; mt < 4; ++mt)
                #pragma unroll
                for (int nt = 0; nt < 4; ++nt)
                    acc[mt][nt] = __builtin_amdgcn_mfma_f32_16x16x32_bf16(
                        af[mt], bfr[nt], acc[mt][nt], 0, 0, 0);
        }
    }

    // ---- stats epilogue via LDS (low VGPR). C/D layout: col=l15, row=q*4+r.
    __syncthreads();                       // all tile ds_reads done
    bf16_t* sh = (bf16_t*)smem;            // [128][130] bf16 = 33280 B
    float*  su = (float*)(smem + 33280);   // u[n0..n0+127]          512 B
    float*  sp = (float*)(smem + 33792);   // [256][3] partials     3072 B

    if (tid < 128) su[tid] = u[n0 + tid];
    float bias4[4];
    #pragma unroll
    for (int nt = 0; nt < 4; ++nt) bias4[nt] = bias[n0 + wc * 64 + nt * 16 + l15];

    #pragma unroll
    for (int mt = 0; mt < 4; ++mt)
        #pragma unroll
        for (int nt = 0; nt < 4; ++nt)
            #pragma unroll
            for (int r = 0; r < 4; ++r) {
                const int rowl = wr * 64 + mt * 16 + q * 4 + r;
                const int coll = wc * 64 + nt * 16 + l15;
                sh[rowl * 130 + coll] = (bf16_t)gelu_fast(acc[mt][nt][r] + bias4[nt]);
            }
    __syncthreads();

    // phase 2: thread = (row, half); reduce 64 cols each
    {
        const int rowl = tid >> 1, half = tid & 1;
        const bf16_t* hp = sh + rowl * 130 + half * 64;
        const float*  up = su + half * 64;
        float s1 = 0.f, s2 = 0.f, dd = 0.f;
        #pragma unroll
        for (int c = 0; c < 64; ++c) {
            const float v = (float)hp[c];
            s1 += v; s2 += v * v; dd += v * up[c];
        }
        sp[tid * 3 + 0] = s1; sp[tid * 3 + 1] = s2; sp[tid * 3 + 2] = dd;
    }
    __syncthreads();
    if (tid < 128) {
        const float* p0 = sp + (2 * tid) * 3;
        const float* p1 = sp + (2 * tid + 1) * 3;
        const size_t idx = (size_t)bx * 32768 + (m0 + tid);
        pS1[idx] = p0[0] + p1[0];
        pS2[idx] = p0[1] + p1[1];
        pD[idx]  = p0[2] + p1[2];
    }
}

// ---------------------------------------------------------------------------
// out_scores: out[t*8+k] = rstd*(D - mu*Gw) + Bw   (32768 threads)
// ---------------------------------------------------------------------------
__global__ __launch_bounds__(256) void out_scores(
        const float* __restrict__ pS1, const float* __restrict__ pS2,
        const float* __restrict__ pD,  const float* __restrict__ gwbw,
        float* __restrict__ out) {
    const int t = blockIdx.x * 256 + threadIdx.x;   // 32768 exactly
    float s1 = 0.f, s2 = 0.f, d = 0.f;
    #pragma unroll
    for (int nt = 0; nt < 12; ++nt) {
        const size_t idx = (size_t)nt * 32768 + t;
        s1 += pS1[idx]; s2 += pS2[idx]; d += pD[idx];
    }
    const float mu   = s1 * (1.0f / 1536.0f);
    const float var  = s2 * (1.0f / 1536.0f) - mu * mu;
    const float rstd = rsqrtf(var + 1e-12f);
    const float v = rstd * (d - mu * gwbw[0]) + gwbw[1];
    const float4 f = make_float4(v, v, v, v);
    float4* o = (float4*)(out + (size_t)t * 8);
    o[0] = f; o[1] = f;
}

// ---------------------------------------------------------------------------
extern "C" void kernel_launch(void* const* d_in, const int* in_sizes, int n_in,
                              void* d_out, int out_size, void* d_ws, size_t ws_size,
                              hipStream_t stream) {
    const float* E   = (const float*)d_in[0];
    const float* W1  = (const float*)d_in[1];
    const float* b1  = (const float*)d_in[2];
    const float* lng = (const float*)d_in[3];
    const float* lnb = (const float*)d_in[4];
    const float* W2  = (const float*)d_in[5];
    const float* b2  = (const float*)d_in[6];
    float* out = (float*)d_out;

    char* w = (char*)d_ws;
    auto carve = [&](size_t bytes) {
        void* p = (void*)w;
        w += (bytes + 255) & ~(size_t)255;
        return p;
    };
    bf16_t* W1t   = (bf16_t*)carve((size_t)1536 * 768 * 2);    //  2.4 MB
    bf16_t* Ebf   = (bf16_t*)carve((size_t)32768 * 768 * 2);   // 50.3 MB
    float*  u     = (float*)carve(1536 * 4);
    float*  gwbw  = (float*)carve(256);
    // Union region: hpart (12.6 MB, written by prep_duo, dead after
    // own_lnlog) overlaps pS1/pS2/pD (4.7 MB, first written by gemm1p,
    // which runs after own_lnlog) — disjoint lifetimes.
    char*   unionr = (char*)carve((size_t)4 * 512 * 1536 * 4); // 12.6 MB
    float*  hpart = (float*)unionr;
    float*  pS1   = (float*)unionr;
    float*  pS2   = (float*)(unionr + (size_t)12 * 32768 * 4);
    float*  pD    = (float*)(unionr + (size_t)24 * 32768 * 4);

    // 1) prep: W1 transpose + own-row k-partials + E->bf16 (fused grid)
    prep_duo<<<12832, 256, 0, stream>>>(E, W1, W1t, hpart, Ebf);
    // 2) own rows: gelu+LN+logits+softmax/argmax; block 511 -> u/Gw/Bw
    own_lnlog<<<512, 512, 0, stream>>>(hpart, b1, lng, lnb, W2, b2,
                                       out, u, gwbw);
    // 3) fused GEMM, both operands bf16 via async DMA
    gemm1p<<<dim3(12, 256), 256, 0, stream>>>(Ebf, W1t, b1, u, pS1, pS2, pD);
    // 4) combine partials -> output 0
    out_scores<<<128, 256, 0, stream>>>(pS1, pS2, pD, gwbw, out);
}